// Round 3
// baseline (839.794 us; speedup 1.0000x reference)
//
#include <hip/hip_runtime.h>
#include <math.h>

#define NWG 16
#define BIGI (1 << 30)

// ---- workspace layout (4-byte units) ----
#define MM_OFF    0        // 64 images x 4 ints
#define BAR_OFF   256      // 64 barriers x 64-int stride = 4096 ints
#define POS2T_OFF 4352     // pos2T[k=256][r=64]
#define H1ST_OFF  20736    // h1sT[unit=256][r=64]
#define HSTEP_OFF 38912    // 32 step-buffers x 1024 floats (4KB-aligned each)
// end: 71680 floats = 286,720 bytes

// ---- output layout (floats) ----
#define OUT_DELTAS 0       // (4,5,4)
#define OUT_PBB    80      // (4,5,4)
#define OUT_LOC    160     // (4,5,2)
#define OUT_SCL    200     // (4,5,2)
#define OUT_MF     240     // (4,16,256)
#define OUT_CONF   16624   // (4,5)
#define OUT_BBOX   16644   // (4,16,4)

// ---- LDS layout for k_main (floats) ----
#define OFF_XG    0        // xg[cc=64][r=64]
#define OFF_PART  4096     // part[ks=4][cc=64][b=4]
#define OFF_P1    5120     // pos1[i=4][256]
#define OFF_BB    6144     // bbox[i=4][4]
#define OFF_E     6160     // lh 1024, x1 1024, x2 512, c1 512, dl 80
#define SMEM_FLOATS 9312

__device__ __forceinline__ float sigmoidf_(float x) { return 1.0f / (1.0f + expf(-x)); }

// Device-coherent store (bypasses local L2 so data reaches the IF coherence
// point; drained by the s_waitcnt vmcnt(0) that __syncthreads emits).
__device__ __forceinline__ void cstore(float* p, float v) {
    __hip_atomic_store(p, v, __ATOMIC_RELAXED, __HIP_MEMORY_SCOPE_AGENT);
}

__device__ __forceinline__ void gbar(int* ctrs, int bidx) {
    __syncthreads();  // drains vmcnt(0): all sc1 stores visible before arrive
    if (threadIdx.x == 0) {
        int* c = ctrs + bidx * 64;
        __hip_atomic_fetch_add(c, 1, __ATOMIC_RELAXED, __HIP_MEMORY_SCOPE_AGENT);
        while (__hip_atomic_load(c, __ATOMIC_RELAXED, __HIP_MEMORY_SCOPE_AGENT) < NWG) {
            __builtin_amdgcn_s_sleep(1);
        }
    }
    __syncthreads();
}

// ---------------- kernel 1: init barrier counters + minmax sentinels ----------------
__global__ void k_init(int* ws) {
    int tid = threadIdx.x;
    ws[MM_OFF + tid] = (tid & 1) ? -1 : BIGI;
    for (int i = 0; i < 16; ++i)
        ws[BAR_OFF + tid + i * 256] = 0;
}

// ---------------- kernel 2: per-image mask min/max ----------------
__global__ __launch_bounds__(256) void k_minmax(const float4* __restrict__ pred,
                                                int* __restrict__ mm) {
    int img = blockIdx.x >> 5;
    int chunk = blockIdx.x & 31;
    int tid = threadIdx.x;
    int base = img * 262144 + chunk * 8192 + tid;
    int xmn = BIGI, xmx = -1, ymn = BIGI, ymx = -1;
#pragma unroll 4
    for (int i = 0; i < 32; ++i) {
        int idx4 = base + i * 256;
        float4 v = pred[idx4];
        int x = (idx4 << 2) & 1023;
        int y = (idx4 >> 8) & 1023;
        bool m0 = v.x > 0.5f, m1 = v.y > 0.5f, m2 = v.z > 0.5f, m3 = v.w > 0.5f;
        int cmn = m0 ? x : (m1 ? x + 1 : (m2 ? x + 2 : (m3 ? x + 3 : BIGI)));
        int cmx = m3 ? x + 3 : (m2 ? x + 2 : (m1 ? x + 1 : (m0 ? x : -1)));
        xmn = min(xmn, cmn);
        xmx = max(xmx, cmx);
        if (m0 | m1 | m2 | m3) { ymn = min(ymn, y); ymx = max(ymx, y); }
    }
    for (int off = 32; off > 0; off >>= 1) {
        xmn = min(xmn, __shfl_down(xmn, off));
        xmx = max(xmx, __shfl_down(xmx, off));
        ymn = min(ymn, __shfl_down(ymn, off));
        ymx = max(ymx, __shfl_down(ymx, off));
    }
    __shared__ int red[4][4];
    int wave = tid >> 6;
    if ((tid & 63) == 0) { red[0][wave] = xmn; red[1][wave] = xmx; red[2][wave] = ymn; red[3][wave] = ymx; }
    __syncthreads();
    if (tid == 0) {
        xmn = min(min(red[0][0], red[0][1]), min(red[0][2], red[0][3]));
        xmx = max(max(red[1][0], red[1][1]), max(red[1][2], red[1][3]));
        ymn = min(min(red[2][0], red[2][1]), min(red[2][2], red[2][3]));
        ymx = max(max(red[3][0], red[3][1]), max(red[3][2], red[3][3]));
        atomicMin(&mm[img * 4 + 0], xmn);
        atomicMax(&mm[img * 4 + 1], xmx);
        atomicMin(&mm[img * 4 + 2], ymn);
        atomicMax(&mm[img * 4 + 3], ymx);
    }
}

// ---------------- kernel 3: persistent fused pos-MLP + 2-layer LSTM + heads ----------------
// 16 wgs x 256 threads. wg w owns units [w*16, w*16+16) -> 64 gate cols.
// Thread roles: dot phase (cc = tid&63 gate col, ks = tid>>6 k-quarter);
// cell phase tid<64: (b = tid>>4, u = tid&15).
__global__ __launch_bounds__(256, 1) void k_main(
    const float* __restrict__ pe_w1, const float* __restrict__ pe_b1,
    const float* __restrict__ pe_w2, const float* __restrict__ pe_b2,
    const float* __restrict__ wih0, const float* __restrict__ whh0,
    const float* __restrict__ bih0, const float* __restrict__ bhh0,
    const float* __restrict__ wih1, const float* __restrict__ whh1,
    const float* __restrict__ bih1, const float* __restrict__ bhh1,
    const float* __restrict__ mp_w1, const float* __restrict__ mp_b1,
    const float* __restrict__ mp_w2, const float* __restrict__ mp_b2,
    const float* __restrict__ mp_w3, const float* __restrict__ mp_b3,
    const float* __restrict__ cf_w1, const float* __restrict__ cf_b1,
    const float* __restrict__ cf_w2, const float* __restrict__ cf_b2,
    float* __restrict__ out, int* __restrict__ wsi, float* __restrict__ wsf) {
    __shared__ float smem[SMEM_FLOATS];
    const int tid = threadIdx.x;
    const int w = blockIdx.x;
    int* ctrs = wsi + BAR_OFF;
    float* pos2T = wsf + POS2T_OFF;
    float* h1sT = wsf + H1ST_OFF;
    float* hstep = wsf + HSTEP_OFF;

    // ---- Phase A: bboxes for images w*4..w*4+4, pos-MLP rows, publish pos2T ----
    if (tid < 4) {
        int img = w * 4 + tid;
        int xmn = wsi[MM_OFF + img * 4 + 0], xmx = wsi[MM_OFF + img * 4 + 1];
        int ymn = wsi[MM_OFF + img * 4 + 2], ymx = wsi[MM_OFF + img * 4 + 3];
        float cx, cy, bw, bh;
        if (xmx >= 0) {
            cx = (float)(xmn + xmx) * (0.5f / 1024.0f);
            cy = (float)(ymn + ymx) * (0.5f / 1024.0f);
            bw = (float)(xmx - xmn) * (1.0f / 1024.0f);
            bh = (float)(ymx - ymn) * (1.0f / 1024.0f);
        } else { cx = 0.5f; cy = 0.5f; bw = 0.1f; bh = 0.1f; }
        smem[OFF_BB + tid * 4 + 0] = cx; smem[OFF_BB + tid * 4 + 1] = cy;
        smem[OFF_BB + tid * 4 + 2] = bw; smem[OFF_BB + tid * 4 + 3] = bh;
        out[OUT_BBOX + img * 4 + 0] = cx; out[OUT_BBOX + img * 4 + 1] = cy;
        out[OUT_BBOX + img * 4 + 2] = bw; out[OUT_BBOX + img * 4 + 3] = bh;
    }
    __syncthreads();
    {   // pos1 for 4 images
        float wv0 = pe_w1[tid], wv1 = pe_w1[256 + tid];
        float wv2 = pe_w1[512 + tid], wv3 = pe_w1[768 + tid];
        float bb = pe_b1[tid];
#pragma unroll
        for (int i = 0; i < 4; ++i) {
            const float* bp = smem + OFF_BB + i * 4;
            float v = bp[0] * wv0 + bp[1] * wv1 + bp[2] * wv2 + bp[3] * wv3 + bb;
            smem[OFF_P1 + i * 256 + tid] = fmaxf(v, 0.0f);
        }
    }
    __syncthreads();
    {   // pos2 for 4 images -> pos2T[k=tid][r=w*4+i]  (sc1: read by all wgs)
        float a0 = pe_b2[tid], a1 = a0, a2 = a0, a3 = a0;
#pragma unroll 4
        for (int k = 0; k < 256; ++k) {
            float wv = pe_w2[k * 256 + tid];
            a0 += smem[OFF_P1 + 0 * 256 + k] * wv;
            a1 += smem[OFF_P1 + 1 * 256 + k] * wv;
            a2 += smem[OFF_P1 + 2 * 256 + k] * wv;
            a3 += smem[OFF_P1 + 3 * 256 + k] * wv;
        }
        float* p = pos2T + tid * 64 + w * 4;
        cstore(p + 0, fmaxf(a0, 0.0f));
        cstore(p + 1, fmaxf(a1, 0.0f));
        cstore(p + 2, fmaxf(a2, 0.0f));
        cstore(p + 3, fmaxf(a3, 0.0f));
    }
    gbar(ctrs, 0);

    const int cc = tid & 63;        // gate col within wg
    const int ks = tid >> 6;        // k-quarter
    const int gcol = (cc >> 4) * 256 + w * 16 + (cc & 15);  // global gate col

    for (int layer = 0; layer < 2; ++layer) {
        const float* whh = layer ? whh1 : whh0;
        const float* wih = layer ? wih1 : wih0;
        const float* bih = layer ? bih1 : bih0;
        const float* bhh = layer ? bhh1 : bhh0;
        const float* src = layer ? h1sT : pos2T;  // [256][64], plain-read safe

        // ---- whh column slice into VGPRs: wreg[j] = whh[ks*64+j*4 .. +4][gcol]
        float4 wreg[16];
#pragma unroll
        for (int j = 0; j < 16; ++j) {
            int kk = ks * 64 + j * 4;
            wreg[j].x = whh[(kk + 0) * 1024 + gcol];
            wreg[j].y = whh[(kk + 1) * 1024 + gcol];
            wreg[j].z = whh[(kk + 2) * 1024 + gcol];
            wreg[j].w = whh[(kk + 3) * 1024 + gcol];
        }

        // ---- xg[cc][r] for this wg's 64 cols, all 64 (b,t) rows ----
        {
            int cq = ks;            // col quad: cols cq*16..+16 (g = cq)
            int r = cc;             // (b,t) row
            int colbase = cq * 256 + w * 16;
            float acc[16];
#pragma unroll
            for (int j = 0; j < 16; ++j) acc[j] = bih[colbase + j];
            for (int k = 0; k < 256; ++k) {
                float s = src[k * 64 + r];
                const float4* wp = (const float4*)(wih + k * 1024 + colbase);
                float4 w0 = wp[0], w1 = wp[1], w2 = wp[2], w3 = wp[3];
                acc[0] += s * w0.x; acc[1] += s * w0.y; acc[2] += s * w0.z; acc[3] += s * w0.w;
                acc[4] += s * w1.x; acc[5] += s * w1.y; acc[6] += s * w1.z; acc[7] += s * w1.w;
                acc[8] += s * w2.x; acc[9] += s * w2.y; acc[10] += s * w2.z; acc[11] += s * w2.w;
                acc[12] += s * w3.x; acc[13] += s * w3.y; acc[14] += s * w3.z; acc[15] += s * w3.w;
            }
#pragma unroll
            for (int j = 0; j < 16; ++j)
                smem[OFF_XG + (cq * 16 + j) * 64 + r] = acc[j];
        }

        float bhh_r[4];
        float cstate = 0.0f;
        if (tid < 64) {
            int u = tid & 15;
#pragma unroll
            for (int g = 0; g < 4; ++g) bhh_r[g] = bhh[g * 256 + w * 16 + u];
        }
        __syncthreads();  // xg ready in LDS

        // ---- 16 recurrent steps ----
        for (int t = 0; t < 16; ++t) {
            if (t > 0) {
                // partial dot: h_prev (plain, fresh per-step buffer) . wreg
                const float* hk = hstep + (layer * 16 + t - 1) * 1024 + ks * 64;
                float a0 = 0.f, a1 = 0.f, a2 = 0.f, a3 = 0.f;
#pragma unroll
                for (int j = 0; j < 16; ++j) {
                    float4 wv = wreg[j];
                    float4 h0 = *(const float4*)(hk + 0 * 256 + j * 4);
                    float4 h1 = *(const float4*)(hk + 1 * 256 + j * 4);
                    float4 h2 = *(const float4*)(hk + 2 * 256 + j * 4);
                    float4 h3 = *(const float4*)(hk + 3 * 256 + j * 4);
                    a0 += h0.x * wv.x + h0.y * wv.y + h0.z * wv.z + h0.w * wv.w;
                    a1 += h1.x * wv.x + h1.y * wv.y + h1.z * wv.z + h1.w * wv.w;
                    a2 += h2.x * wv.x + h2.y * wv.y + h2.z * wv.z + h2.w * wv.w;
                    a3 += h3.x * wv.x + h3.y * wv.y + h3.z * wv.z + h3.w * wv.w;
                }
                float4 pv; pv.x = a0; pv.y = a1; pv.z = a2; pv.w = a3;
                ((float4*)(smem + OFF_PART))[ks * 64 + cc] = pv;
                __syncthreads();
            }
            if (tid < 64) {  // cell update: (b, u)
                int b = tid >> 4, u = tid & 15;
                float g4[4];
#pragma unroll
                for (int g = 0; g < 4; ++g) {
                    int c2 = g * 16 + u;
                    float s = smem[OFF_XG + c2 * 64 + b * 16 + t] + bhh_r[g];
                    if (t > 0) {
                        s += smem[OFF_PART + 0 * 256 + c2 * 4 + b] +
                             smem[OFF_PART + 1 * 256 + c2 * 4 + b] +
                             smem[OFF_PART + 2 * 256 + c2 * 4 + b] +
                             smem[OFF_PART + 3 * 256 + c2 * 4 + b];
                    }
                    g4[g] = s;
                }
                float i_ = sigmoidf_(g4[0]), f_ = sigmoidf_(g4[1]);
                float gg = tanhf(g4[2]), o_ = sigmoidf_(g4[3]);
                cstate = f_ * cstate + i_ * gg;
                float h = o_ * tanhf(cstate);
                int unit = w * 16 + u;
                cstore(&hstep[(layer * 16 + t) * 1024 + b * 256 + unit], h);
                if (layer == 0) cstore(&h1sT[unit * 64 + b * 16 + t], h);
                else out[OUT_MF + (b * 16 + t) * 256 + unit] = h;
            }
            gbar(ctrs, 1 + layer * 16 + t);
        }
    }

    // ---- Phase E: heads (wg 0). last_hidden = hstep buffer 31 (plain, fresh) ----
    if (w == 0) {
        float* lh = smem + OFF_E;
        float* x1 = lh + 1024;
        float* x2 = x1 + 1024;
        float* c1 = x2 + 512;
        float* dl = c1 + 512;
        ((float4*)lh)[tid] = ((const float4*)(hstep + 31 * 1024))[tid];
        __syncthreads();
        {   // x1 = relu(lh @ mp_w1 + mp_b1)  (4 x 256)
            int bb = tid >> 6, c0 = (tid & 63) * 4;
            float a0 = mp_b1[c0], a1 = mp_b1[c0 + 1], a2 = mp_b1[c0 + 2], a3 = mp_b1[c0 + 3];
            const float* lhb = lh + bb * 256;
#pragma unroll 4
            for (int k = 0; k < 256; ++k) {
                float lv = lhb[k];
                float4 w4 = *(const float4*)(mp_w1 + k * 256 + c0);
                a0 += lv * w4.x; a1 += lv * w4.y; a2 += lv * w4.z; a3 += lv * w4.w;
            }
            x1[bb * 256 + c0 + 0] = fmaxf(a0, 0.0f);
            x1[bb * 256 + c0 + 1] = fmaxf(a1, 0.0f);
            x1[bb * 256 + c0 + 2] = fmaxf(a2, 0.0f);
            x1[bb * 256 + c0 + 3] = fmaxf(a3, 0.0f);
        }
        if (tid < 128) {  // c1 = relu(lh @ cf_w1 + cf_b1)  (4 x 128)
            int bb = tid >> 5, c0 = (tid & 31) * 4;
            float a0 = cf_b1[c0], a1 = cf_b1[c0 + 1], a2 = cf_b1[c0 + 2], a3 = cf_b1[c0 + 3];
            const float* lhb = lh + bb * 256;
#pragma unroll 4
            for (int k = 0; k < 256; ++k) {
                float lv = lhb[k];
                float4 w4 = *(const float4*)(cf_w1 + k * 128 + c0);
                a0 += lv * w4.x; a1 += lv * w4.y; a2 += lv * w4.z; a3 += lv * w4.w;
            }
            c1[bb * 128 + c0 + 0] = fmaxf(a0, 0.0f);
            c1[bb * 128 + c0 + 1] = fmaxf(a1, 0.0f);
            c1[bb * 128 + c0 + 2] = fmaxf(a2, 0.0f);
            c1[bb * 128 + c0 + 3] = fmaxf(a3, 0.0f);
        }
        __syncthreads();
        if (tid < 128) {  // x2 = relu(x1 @ mp_w2 + mp_b2)  (4 x 128)
            int bb = tid >> 5, c0 = (tid & 31) * 4;
            float a0 = mp_b2[c0], a1 = mp_b2[c0 + 1], a2 = mp_b2[c0 + 2], a3 = mp_b2[c0 + 3];
            const float* x1b = x1 + bb * 256;
#pragma unroll 4
            for (int k = 0; k < 256; ++k) {
                float xv = x1b[k];
                float4 w4 = *(const float4*)(mp_w2 + k * 128 + c0);
                a0 += xv * w4.x; a1 += xv * w4.y; a2 += xv * w4.z; a3 += xv * w4.w;
            }
            x2[bb * 128 + c0 + 0] = fmaxf(a0, 0.0f);
            x2[bb * 128 + c0 + 1] = fmaxf(a1, 0.0f);
            x2[bb * 128 + c0 + 2] = fmaxf(a2, 0.0f);
            x2[bb * 128 + c0 + 3] = fmaxf(a3, 0.0f);
        }
        __syncthreads();
        if (tid < 80) {  // deltas = x2 @ mp_w3 + mp_b3  (4 x 20)
            int bb = tid / 20, j = tid - bb * 20;
            float a = mp_b3[j];
            const float* x2b = x2 + bb * 128;
#pragma unroll 4
            for (int k = 0; k < 128; ++k) a += x2b[k] * mp_w3[k * 20 + j];
            dl[bb * 20 + j] = a;
            out[OUT_DELTAS + bb * 20 + j] = a;
        }
        if (tid >= 96 && tid < 116) {  // confidence (4 x 5)
            int idx = tid - 96;
            int bb = idx / 5, j = idx - bb * 5;
            float a = cf_b2[j];
            const float* c1b = c1 + bb * 128;
#pragma unroll 4
            for (int k = 0; k < 128; ++k) a += c1b[k] * cf_w2[k * 5 + j];
            out[OUT_CONF + bb * 5 + j] = sigmoidf_(a);
        }
        __syncthreads();
        if (tid < 16) {  // cumsum of deltas onto last bbox
            int bb = tid >> 2, j = tid & 3;
            int img = bb * 16 + 15;
            int xmn = wsi[MM_OFF + img * 4 + 0], xmx = wsi[MM_OFF + img * 4 + 1];
            int ymn = wsi[MM_OFF + img * 4 + 2], ymx = wsi[MM_OFF + img * 4 + 3];
            float v[4];
            if (xmx >= 0) {
                v[0] = (float)(xmn + xmx) * (0.5f / 1024.0f);
                v[1] = (float)(ymn + ymx) * (0.5f / 1024.0f);
                v[2] = (float)(xmx - xmn) * (1.0f / 1024.0f);
                v[3] = (float)(ymx - ymn) * (1.0f / 1024.0f);
            } else { v[0] = 0.5f; v[1] = 0.5f; v[2] = 0.1f; v[3] = 0.1f; }
            float acc = v[j];
            for (int h = 0; h < 5; ++h) {
                acc += dl[bb * 20 + h * 4 + j];
                out[OUT_PBB + bb * 20 + h * 4 + j] = acc;
                if (j < 2) out[OUT_LOC + bb * 10 + h * 2 + j] = acc;
                else out[OUT_SCL + bb * 10 + h * 2 + (j - 2)] = acc;
            }
        }
    }
}

extern "C" void kernel_launch(void* const* d_in, const int* in_sizes, int n_in,
                              void* d_out, int out_size, void* d_ws, size_t ws_size,
                              hipStream_t stream) {
    (void)in_sizes; (void)n_in; (void)out_size; (void)ws_size;
    const float* pred = (const float*)d_in[1];  // d_in[0] = features (unused)
    const float* pe_w1 = (const float*)d_in[2];
    const float* pe_b1 = (const float*)d_in[3];
    const float* pe_w2 = (const float*)d_in[4];
    const float* pe_b2 = (const float*)d_in[5];
    const float* wih0 = (const float*)d_in[6];
    const float* whh0 = (const float*)d_in[7];
    const float* bih0 = (const float*)d_in[8];
    const float* bhh0 = (const float*)d_in[9];
    const float* wih1 = (const float*)d_in[10];
    const float* whh1 = (const float*)d_in[11];
    const float* bih1 = (const float*)d_in[12];
    const float* bhh1 = (const float*)d_in[13];
    const float* mp_w1 = (const float*)d_in[14];
    const float* mp_b1 = (const float*)d_in[15];
    const float* mp_w2 = (const float*)d_in[16];
    const float* mp_b2 = (const float*)d_in[17];
    const float* mp_w3 = (const float*)d_in[18];
    const float* mp_b3 = (const float*)d_in[19];
    const float* cf_w1 = (const float*)d_in[20];
    const float* cf_b1 = (const float*)d_in[21];
    const float* cf_w2 = (const float*)d_in[22];
    const float* cf_b2 = (const float*)d_in[23];
    float* out = (float*)d_out;
    int* wsi = (int*)d_ws;
    float* wsf = (float*)d_ws;

    hipLaunchKernelGGL(k_init, dim3(1), dim3(256), 0, stream, wsi);
    hipLaunchKernelGGL(k_minmax, dim3(64 * 32), dim3(256), 0, stream,
                       (const float4*)pred, wsi + MM_OFF);
    hipLaunchKernelGGL(k_main, dim3(NWG), dim3(256), 0, stream,
                       pe_w1, pe_b1, pe_w2, pe_b2,
                       wih0, whh0, bih0, bhh0,
                       wih1, whh1, bih1, bhh1,
                       mp_w1, mp_b1, mp_w2, mp_b2, mp_w3, mp_b3,
                       cf_w1, cf_b1, cf_w2, cf_b2,
                       out, wsi, wsf);
}